// Round 4
// baseline (354.015 us; speedup 1.0000x reference)
//
#include <hip/hip_runtime.h>
#include <hip/hip_bf16.h>

// RetrieverBase: q[64][32][128] f32, p[128][180][128] f32
// out = concat(term_relevance[64][128][32][180], query_maxsim[64][128][32], relevance[64][128])
#define A_N 64
#define B_N 128
#define Q_N 32
#define D_N 180
#define V_N 128

typedef __attribute__((ext_vector_type(8))) short bf16x8;   // 8 bf16 (4 VGPRs)
typedef __attribute__((ext_vector_type(4))) float f32x4;

__device__ __forceinline__ short f2bf(float f) {
  __hip_bfloat16 h = __float2bfloat16(f);
  return (short)__builtin_bit_cast(unsigned short, h);
}

__device__ __forceinline__ bf16x8 pack8(const f32x4& lo, const f32x4& hi) {
  bf16x8 v;
  v[0] = f2bf(lo[0]); v[1] = f2bf(lo[1]); v[2] = f2bf(lo[2]); v[3] = f2bf(lo[3]);
  v[4] = f2bf(hi[0]); v[5] = f2bf(hi[1]); v[6] = f2bf(hi[2]); v[7] = f2bf(hi[3]);
  return v;
}

// Grid 256 (= #CUs): one block per (b, a-half). Block = 1024 threads = 16 waves.
// Stage p[b] ONCE into LDS as bf16 (46KB, XOR-swizzled), then each wave
// independently computes the full C[32x180] = p[b] * q[a]^T for 2 a's.
// No barriers after staging; maxsim/relevance reduced in-register per wave.
//
// LDS swizzle: row r (256B = 16 x 16B chunks); chunk slot' = (slot&8) |
// ((slot&7) ^ (r&7)). Fragment read group = 16 lanes, same slot, rows
// r0..r0+15 -> 8 distinct chunk positions x 2 rows 2048B apart (same bank)
// = 2-way conflict = free (m136).
__global__ __launch_bounds__(1024, 4) void score_kernel(
    const float* __restrict__ q, const float* __restrict__ p,
    float* __restrict__ out) {
  const int bid = blockIdx.x;
  const int b   = bid & (B_N - 1);
  const int ah  = bid >> 7;          // a-half: 0 or 1 (bid, bid+128 share b -> same XCD)
  const int tid = threadIdx.x;
  const int wv  = tid >> 6;          // 0..15
  const int lane = tid & 63;
  const int l16 = lane & 15;
  const int g   = lane >> 4;         // 0..3

  const float* __restrict__ pb = p + (size_t)b * D_N * V_N;

  // ---- stage p[b] -> LDS bf16, swizzled; 2880 16B-chunks over 1024 threads ----
  __shared__ ushort plds[D_N * V_N];   // 46080 B
  for (int c = tid; c < D_N * (V_N / 8); c += 1024) {
    const int r    = c >> 4;
    const int slot = c & 15;
    const int sp   = (slot & 8) | ((slot & 7) ^ (r & 7));
    const float* s = pb + (size_t)r * V_N + slot * 8;
    bf16x8 v = pack8(*reinterpret_cast<const f32x4*>(s),
                     *reinterpret_cast<const f32x4*>(s + 4));
    *reinterpret_cast<bf16x8*>(&plds[r * V_N + sp * 8]) = v;
  }
  __syncthreads();

  const size_t TERM_SZ = (size_t)A_N * B_N * Q_N * D_N;

#pragma unroll 1
  for (int j = 0; j < 2; ++j) {
    const int a = ah * 32 + wv * 2 + j;
    const float* __restrict__ qa = q + (size_t)a * Q_N * V_N;

    // q as B-fragments: B[k][col=q]; lane reads q[qt*16+l16][kk*32+g*8 ..+7]
    bf16x8 qf[2][4];
#pragma unroll
    for (int qt = 0; qt < 2; ++qt)
#pragma unroll
      for (int kk = 0; kk < 4; ++kk) {
        const float* s = qa + (size_t)(qt * 16 + l16) * V_N + kk * 32 + g * 8;
        qf[qt][kk] = pack8(*reinterpret_cast<const f32x4*>(s),
                           *reinterpret_cast<const f32x4*>(s + 4));
      }

    float qmax[2] = {-INFINITY, -INFINITY};
    const size_t outbase = ((size_t)a * B_N + b) * (size_t)(Q_N * D_N);

#pragma unroll
    for (int dt = 0; dt < 12; ++dt) {
      const int drow = dt * 16 + l16;
      const int dr   = drow < D_N ? drow : (D_N - 1);  // tail clamp, max-safe

      // A-fragment from LDS: p-row dr, k = kk*32 + g*8 .. +7  (chunk slot kk*4+g)
      bf16x8 pf[4];
#pragma unroll
      for (int kk = 0; kk < 4; ++kk) {
        const int slot = kk * 4 + g;
        const int sp   = (slot & 8) | ((slot & 7) ^ (dr & 7));
        pf[kk] = *reinterpret_cast<const bf16x8*>(&plds[dr * V_N + sp * 8]);
      }

      f32x4 acc0 = (f32x4){0.f, 0.f, 0.f, 0.f};
      f32x4 acc1 = (f32x4){0.f, 0.f, 0.f, 0.f};
#pragma unroll
      for (int kk = 0; kk < 4; ++kk) {
        acc0 = __builtin_amdgcn_mfma_f32_16x16x32_bf16(pf[kk], qf[0][kk], acc0, 0, 0, 0);
        acc1 = __builtin_amdgcn_mfma_f32_16x16x32_bf16(pf[kk], qf[1][kk], acc1, 0, 0, 0);
      }

      // C/D layout: col = l16 = q, row = g*4 + reg = d within tile
      const int d0 = dt * 16 + g * 4;
      qmax[0] = fmaxf(qmax[0], fmaxf(fmaxf(acc0[0], acc0[1]), fmaxf(acc0[2], acc0[3])));
      qmax[1] = fmaxf(qmax[1], fmaxf(fmaxf(acc1[0], acc1[1]), fmaxf(acc1[2], acc1[3])));
      if (d0 < D_N) {   // only dt==11, g>0 masked
        *reinterpret_cast<f32x4*>(out + outbase + (size_t)l16 * D_N + d0) = acc0;
        *reinterpret_cast<f32x4*>(out + outbase + (size_t)(16 + l16) * D_N + d0) = acc1;
      }
    }

    // reduce max across the 4 g-groups (different d sub-rows, same q)
#pragma unroll
    for (int qt = 0; qt < 2; ++qt) {
      float v = qmax[qt];
      v = fmaxf(v, __shfl_xor(v, 16, 64));
      v = fmaxf(v, __shfl_xor(v, 32, 64));
      qmax[qt] = v;
    }

    if (lane < 16) {   // maxsim for q = qt*16 + lane
      float* ms = out + TERM_SZ + ((size_t)a * B_N + b) * Q_N;
      ms[lane]      = qmax[0];
      ms[16 + lane] = qmax[1];
    }

    // relevance = sum over 32 q of maxsim
    float s = qmax[0] + qmax[1];
    s += __shfl_xor(s, 1, 64);
    s += __shfl_xor(s, 2, 64);
    s += __shfl_xor(s, 4, 64);
    s += __shfl_xor(s, 8, 64);
    if (lane == 0)
      out[TERM_SZ + (size_t)A_N * B_N * Q_N + (size_t)a * B_N + b] = s;
  }
}

extern "C" void kernel_launch(void* const* d_in, const int* in_sizes, int n_in,
                              void* d_out, int out_size, void* d_ws, size_t ws_size,
                              hipStream_t stream) {
  const float* q = (const float*)d_in[0];
  const float* p = (const float*)d_in[1];
  float* out = (float*)d_out;
  dim3 grid(256);    // one block per CU: 128 b x 2 a-halves
  dim3 block(1024);  // 16 waves; wave handles 2 a's end-to-end
  hipLaunchKernelGGL(score_kernel, grid, block, 0, stream, q, p, out);
}

// Round 5
// 109.095 us; speedup vs baseline: 3.2450x; 3.2450x over previous
//
#include <hip/hip_runtime.h>
#include <hip/hip_bf16.h>

// RetrieverBase: q[64][32][128] f32, p[128][180][128] f32
// out = concat(term_relevance[64][128][32][180], query_maxsim[64][128][32], relevance[64][128])
#define A_N 64
#define B_N 128
#define Q_N 32
#define D_N 180
#define V_N 128

typedef __attribute__((ext_vector_type(8))) short bf16x8;   // 8 bf16 (4 VGPRs)
typedef __attribute__((ext_vector_type(4))) float f32x4;

__device__ __forceinline__ short f2bf(float f) {
  __hip_bfloat16 h = __float2bfloat16(f);
  return (short)__builtin_bit_cast(unsigned short, h);
}

__device__ __forceinline__ bf16x8 pack8(const f32x4& lo, const f32x4& hi) {
  bf16x8 v;
  v[0] = f2bf(lo[0]); v[1] = f2bf(lo[1]); v[2] = f2bf(lo[2]); v[3] = f2bf(lo[3]);
  v[4] = f2bf(hi[0]); v[5] = f2bf(hi[1]); v[6] = f2bf(hi[2]); v[7] = f2bf(hi[3]);
  return v;
}

// Grid 2048 = 32 bg x 64 a (a fast => same-bg blocks round-robin the XCDs and
// share p[bg*4..+4) in each XCD's L2). Block = 4 waves, cooperating on ONE
// (a,b) at a time (4 pairs, b = bg*4+i). Wave wv owns d-tiles {wv, wv+4, wv+8}.
// C[32][180] is staged in double-buffered LDS, then streamed to HBM LINEARLY:
// 256 thr x 16B ascending => every 64B line written once, fully. This removes
// the partial-line RMW that capped writes at ~2 TB/s in R1-R4.
__global__ __launch_bounds__(256, 3) void score_kernel(
    const float* __restrict__ q, const float* __restrict__ p,
    float* __restrict__ out) {
  const int bid  = blockIdx.x;
  const int a    = bid & 63;
  const int bg   = bid >> 6;
  const int tid  = threadIdx.x;
  const int wv   = tid >> 6;
  const int lane = tid & 63;
  const int l16  = lane & 15;
  const int g    = lane >> 4;   // 0..3

  __shared__ float cbuf[2][Q_N * D_N];   // 2 x 23040 B
  __shared__ float smax[2][4][Q_N];      // per-wave row maxes, double-buffered

  const float* __restrict__ qa = q + (size_t)a * Q_N * V_N;

  // q as B-fragments (loaded once, reused for all 4 pairs):
  // B[k][col=q]; lane reads q[qt*16+l16][kk*32+g*8 ..+7]
  bf16x8 qf[2][4];
#pragma unroll
  for (int qt = 0; qt < 2; ++qt)
#pragma unroll
    for (int kk = 0; kk < 4; ++kk) {
      const float* s = qa + (size_t)(qt * 16 + l16) * V_N + kk * 32 + g * 8;
      qf[qt][kk] = pack8(*reinterpret_cast<const f32x4*>(s),
                         *reinterpret_cast<const f32x4*>(s + 4));
    }

  const size_t TERM_SZ = (size_t)A_N * B_N * Q_N * D_N;

#define LOADRAW(dst, dt)                                                     \
  {                                                                          \
    const int drow = (dt) * 16 + l16;                                        \
    const int dr   = drow < D_N ? drow : (D_N - 1);                          \
    const float* s = pb + (size_t)dr * V_N + g * 8;                          \
    _Pragma("unroll")                                                        \
    for (int kk = 0; kk < 4; ++kk) {                                         \
      dst[2 * kk]     = *reinterpret_cast<const f32x4*>(s + kk * 32);        \
      dst[2 * kk + 1] = *reinterpret_cast<const f32x4*>(s + kk * 32 + 4);    \
    }                                                                        \
  }

  for (int i = 0; i < 4; ++i) {
    const int b = bg * 4 + i;
    const float* __restrict__ pb = p + (size_t)b * D_N * V_N;
    float* cb = cbuf[i & 1];

    float qm0 = -INFINITY, qm1 = -INFINITY;

    f32x4 rawA[8], rawB[8];
    LOADRAW(rawA, wv);

#pragma unroll
    for (int ii = 0; ii < 3; ++ii) {
      const int dt = wv + ii * 4;          // this wave's d-tile
      f32x4* cur = (ii & 1) ? rawB : rawA;
      f32x4* nxt = (ii & 1) ? rawA : rawB;
      if (ii < 2) LOADRAW(nxt, dt + 4);    // prefetch next tile

      bf16x8 pf[4];
#pragma unroll
      for (int kk = 0; kk < 4; ++kk)
        pf[kk] = pack8(cur[2 * kk], cur[2 * kk + 1]);

      f32x4 acc0 = (f32x4){0.f, 0.f, 0.f, 0.f};
      f32x4 acc1 = (f32x4){0.f, 0.f, 0.f, 0.f};
#pragma unroll
      for (int kk = 0; kk < 4; ++kk) {
        acc0 = __builtin_amdgcn_mfma_f32_16x16x32_bf16(pf[kk], qf[0][kk], acc0, 0, 0, 0);
        acc1 = __builtin_amdgcn_mfma_f32_16x16x32_bf16(pf[kk], qf[1][kk], acc1, 0, 0, 0);
      }

      // C/D layout: col=l16=q, row=g*4+reg=d-in-tile. Tail tile clamps p-row
      // to 179 -> duplicate values, max-safe, masked from the LDS write.
      const int d0 = dt * 16 + g * 4;
      qm0 = fmaxf(qm0, fmaxf(fmaxf(acc0[0], acc0[1]), fmaxf(acc0[2], acc0[3])));
      qm1 = fmaxf(qm1, fmaxf(fmaxf(acc1[0], acc1[1]), fmaxf(acc1[2], acc1[3])));
      if (d0 < D_N) {
        *reinterpret_cast<f32x4*>(&cb[l16 * D_N + d0])        = acc0;
        *reinterpret_cast<f32x4*>(&cb[(16 + l16) * D_N + d0]) = acc1;
      }
    }

    // wave-local max over the 4 g-groups (different d sub-rows, same q)
    qm0 = fmaxf(qm0, __shfl_xor(qm0, 16, 64));
    qm0 = fmaxf(qm0, __shfl_xor(qm0, 32, 64));
    qm1 = fmaxf(qm1, __shfl_xor(qm1, 16, 64));
    qm1 = fmaxf(qm1, __shfl_xor(qm1, 32, 64));
    if (lane < 16) {
      smax[i & 1][wv][lane]      = qm0;
      smax[i & 1][wv][16 + lane] = qm1;
    }

    __syncthreads();   // cbuf + smax for pair i complete

    // ---- linear cooperative store: full lines, each written exactly once ----
    const size_t outbase = ((size_t)a * B_N + b) * (size_t)(Q_N * D_N);
    for (int c = tid; c < Q_N * D_N / 4; c += 256) {   // 1440 x 16B chunks
      f32x4 v = *reinterpret_cast<const f32x4*>(&cb[c * 4]);
      *reinterpret_cast<f32x4*>(out + outbase + (size_t)c * 4) = v;
    }

    if (tid < Q_N) {   // finalize maxsim + relevance for pair i
      const float m = fmaxf(fmaxf(smax[i & 1][0][tid], smax[i & 1][1][tid]),
                            fmaxf(smax[i & 1][2][tid], smax[i & 1][3][tid]));
      out[TERM_SZ + ((size_t)a * B_N + b) * Q_N + tid] = m;
      float s = m;
      s += __shfl_xor(s, 1, 64);
      s += __shfl_xor(s, 2, 64);
      s += __shfl_xor(s, 4, 64);
      s += __shfl_xor(s, 8, 64);
      s += __shfl_xor(s, 16, 64);
      if (tid == 0)
        out[TERM_SZ + (size_t)A_N * B_N * Q_N + (size_t)a * B_N + b] = s;
    }
    // next pair writes the OTHER cbuf/smax buffer; the barrier above (next
    // iteration) drains this pair's ds_reads before its buffer is reused.
  }
#undef LOADRAW
}

extern "C" void kernel_launch(void* const* d_in, const int* in_sizes, int n_in,
                              void* d_out, int out_size, void* d_ws, size_t ws_size,
                              hipStream_t stream) {
  const float* q = (const float*)d_in[0];
  const float* p = (const float*)d_in[1];
  float* out = (float*)d_out;
  dim3 grid(2048);   // 32 bg x 64 a
  dim3 block(256);   // 4 waves cooperating per (a,b) pair
  hipLaunchKernelGGL(score_kernel, grid, block, 0, stream, q, p, out);
}